// Round 9
// baseline (30342.615 us; speedup 1.0000x reference)
//
#include <hip/hip_runtime.h>
#include <stdint.h>

// LSTM (linear cell/output act) h_last. S=8192, D_IN=1024, H=2048.
// Persistent: 256 WGs x 256 thr, 1 WG/CU. WG owns 8 h-indices (32 cols).
// Thread (kc=tid>>3, cg=tid&7): 4 gate-cols of h-index cg, k-chunk kc.
//   U slice in regs ureg[4][32], W slice in regs wreg[4][16] (f16x2).
// TWO-LEVEL EXCHANGE:
//   tier 1: producers publish 8 h as 4x u64 {tag32|f16x2} to LLC hbuf
//           (agent-scope). Only 8 LEADER WGs (one per XCD, elected via
//           s_getreg(XCC_ID)+atomic counter) poll hbuf, depth-2 pipelined.
//   tier 2: leaders mirror validated u64s to an XCD-local buffer with sc0
//           stores (own L2); consumer WGs poll mirror with sc0 loads
//           (L1-bypass, ~250cy L2 hit). Leaders ZERO their mirror at the
//           prologue (kills stale-L2-tags-across-replays; consumers' first
//           mirror read at t=2 is causally after that zeroing).
//   Tags protect every u64 in both tiers; 16B store/load transactions can't
//   tear a {tag,val} pair. Sticky fallback: 128 futile mirror rounds ->
//   permanent direct LLC poll (r5 path) for that thread.
// POST-MORTEMS ENCODED HERE:
//  - r2: partial unroll -> ureg/wreg in scratch (VGPR=80, 207GB fetch, 2.7x).
//  - r3: guarded per-slot polls serialize (8 x LLC latency/round).
//  - r4: 64B tight polls -> contention collapse (38ms).
//  - r5: 32B + sleep(2) = 26.2ms BEST flat design.
//  - r6: depth-2 no-sleep, all WGs -> 32.3ms. Poll traffic is controlling.
//  - r7: 8B tag + 32B confirm = 27.7ms. Flat LLC poll floor ~7.5Kcy/step.
//  - r8: HIP uint4 is a STRUCT; asm "v" operands need ext_vector_type.

#define S_LEN   8192
#define D_INP   1024
#define HDIM    2048
#define FH      8192
#define NWG     256
#define TPB     256
#define XB      8
#define MIRROR_ROUNDS 128

typedef _Float16 half2_t __attribute__((ext_vector_type(2)));
typedef uint32_t u32x4   __attribute__((ext_vector_type(4)));

#if defined(__has_builtin)
#if __has_builtin(__builtin_amdgcn_fdot2)
#define HAVE_FDOT2 1
#endif
#endif

__device__ __forceinline__ float fdot2f(uint32_t a, uint32_t b, float c) {
#ifdef HAVE_FDOT2
    return __builtin_amdgcn_fdot2(__builtin_bit_cast(half2_t, a),
                                  __builtin_bit_cast(half2_t, b), c, false);
#else
    half2_t ha = __builtin_bit_cast(half2_t, a);
    half2_t hb = __builtin_bit_cast(half2_t, b);
    c = fmaf((float)ha.x, (float)hb.x, c);
    c = fmaf((float)ha.y, (float)hb.y, c);
    return c;
#endif
}

__device__ __forceinline__ uint32_t pack2(float a, float b) {
    half2_t h;
    h.x = (_Float16)a;
    h.y = (_Float16)b;
    return __builtin_bit_cast(uint32_t, h);
}

__device__ __forceinline__ float sigmoidf_fast(float z) {
    return 1.0f / (1.0f + __expf(-z));
}

__device__ __forceinline__ unsigned long long ald(const unsigned long long* p) {
    return __hip_atomic_load(p, __ATOMIC_RELAXED, __HIP_MEMORY_SCOPE_AGENT);
}

// 32B load, L1-bypassed (sc0): reads own-XCD L2.
__device__ __forceinline__ void ld32_sc0(unsigned long long addr,
                                         u32x4& lo, u32x4& hi) {
    asm volatile("global_load_dwordx4 %0, %2, off sc0\n\t"
                 "global_load_dwordx4 %1, %2, off offset:16 sc0\n\t"
                 "s_waitcnt vmcnt(0)"
                 : "=&v"(lo), "=&v"(hi)
                 : "v"(addr)
                 : "memory");
}

// 32B store, write-through L1 (sc0) into own-XCD L2, drained.
__device__ __forceinline__ void st32_sc0(unsigned long long addr,
                                         u32x4 lo, u32x4 hi) {
    asm volatile("global_store_dwordx4 %0, %1, off sc0\n\t"
                 "global_store_dwordx4 %0, %2, off offset:16 sc0\n\t"
                 "s_waitcnt vmcnt(0)"
                 :: "v"(addr), "v"(lo), "v"(hi)
                 : "memory");
}

extern "C" __global__ void __launch_bounds__(TPB, 1)
lstm_persist(const float* __restrict__ x, const float* __restrict__ W,
             const float* __restrict__ U, const float* __restrict__ b,
             float* __restrict__ out, unsigned long long* __restrict__ hbuf)
{
    __shared__ __align__(16) uint32_t xl[XB * 640];
    __shared__ __align__(16) uint32_t hl[32 * 36];
    __shared__ __align__(16) float    zz[4 * 8 * 4];
    __shared__ int s_xcd, s_rank;

    const int tid = threadIdx.x;
    const int wg  = blockIdx.x;
    const int cg  = tid & 7;
    const int kc  = tid >> 3;
    const int w   = tid >> 6;

    // ws layout (u64 units): [0..2047] hbuf | [2048..34815] mirror | counters
    unsigned long long* const mir = hbuf + 2048;   // 16 xcd x 2 par x 1024
    int* const cnt = (int*)(hbuf + 34816);

    // ---- leader election: one leader WG per XCD ----
    if (tid == 0) {
        // s_getreg imm = id | (offset<<6) | ((size-1)<<11); HW_REG_XCC_ID=20
        const int id = __builtin_amdgcn_s_getreg(20 | (31 << 11)) & 15;
        s_xcd  = id;
        s_rank = atomicAdd(&cnt[id], 1);
    }
    __syncthreads();
    const int  xcd    = s_xcd;
    const bool leader = (s_rank == 0);

    // ---- prologue: leader zeroes its XCD's mirror (kills stale L2 tags) ----
    if (leader) {
        const u32x4 z = {0u, 0u, 0u, 0u};
        st32_sc0((unsigned long long)(mir + (xcd * 2 + 0) * 1024 + tid * 4), z, z);
        st32_sc0((unsigned long long)(mir + (xcd * 2 + 1) * 1024 + tid * 4), z, z);
    }

    // ---- one-time: weights -> registers (FULL unroll, static indices) ----
    uint32_t ureg[4][32];
    uint32_t wreg[4][16];
#pragma unroll
    for (int g = 0; g < 4; ++g) {
        const int col = g * HDIM + wg * 8 + cg;
#pragma unroll
        for (int p = 0; p < 32; ++p) {
            const int k0 = kc * 64 + 2 * p;
            ureg[g][p] = pack2(U[(size_t)k0 * FH + col],
                               U[(size_t)(k0 + 1) * FH + col]);
        }
#pragma unroll
        for (int p = 0; p < 16; ++p) {
            const int k0 = kc * 32 + 2 * p;
            wreg[g][p] = pack2(W[(size_t)k0 * FH + col],
                               W[(size_t)(k0 + 1) * FH + col]);
        }
    }
    float bias[4] = {0.f, 0.f, 0.f, 0.f};
    if (tid < 8) {
#pragma unroll
        for (int g = 0; g < 4; ++g) bias[g] = b[g * HDIM + wg * 8 + cg];
    }
    float cst = 0.0f;

    // ---- x prefetch regs ----
    const int xr  = tid >> 5;
    const int kcw = tid & 31;
    float4 pf[8];
    {
        const float4* src = (const float4*)(x + (size_t)xr * D_INP + kcw * 32);
#pragma unroll
        for (int q = 0; q < 8; ++q) pf[q] = src[q];
    }

    unsigned long long* const hb0 = hbuf;
    unsigned long long* const hb1 = hbuf + 1024;
    bool mirror_ok = true;

    for (int t = 0; t < S_LEN; ++t) {
        unsigned long long* const gsrc = ((t & 1) ? hb1 : hb0) + tid * 4;
        const bool direct_mode = leader || (t == 1) || !mirror_ok;
        unsigned long long a0, a1, a2, a3;
        if (t > 0 && direct_mode) {   // early issue: LLC batch in flight
            a0 = ald(gsrc + 0); a1 = ald(gsrc + 1);
            a2 = ald(gsrc + 2); a3 = ald(gsrc + 3);
        }

        const int s = t & (XB - 1);
        if (s == 0) {
            uint32_t* dst = &xl[xr * 640 + kcw * 20];
#pragma unroll
            for (int q = 0; q < 4; ++q) {
                uint4 v;
                v.x = pack2(pf[2 * q].x, pf[2 * q].y);
                v.y = pack2(pf[2 * q].z, pf[2 * q].w);
                v.z = pack2(pf[2 * q + 1].x, pf[2 * q + 1].y);
                v.w = pack2(pf[2 * q + 1].z, pf[2 * q + 1].w);
                *(uint4*)(dst + q * 4) = v;
            }
            __syncthreads();
            if (t + XB < S_LEN) {
                const float4* src = (const float4*)(
                    x + (size_t)(t + XB + xr) * D_INP + kcw * 32);
#pragma unroll
                for (int q = 0; q < 8; ++q) pf[q] = src[q];
            }
        }

        // ---- x-part ----
        float acc[4] = {0.f, 0.f, 0.f, 0.f};
        {
            uint32_t xp[16];
            const uint32_t* xpp = &xl[s * 640 + kc * 20];
            *(uint4*)&xp[0]  = *(const uint4*)(xpp + 0);
            *(uint4*)&xp[4]  = *(const uint4*)(xpp + 4);
            *(uint4*)&xp[8]  = *(const uint4*)(xpp + 8);
            *(uint4*)&xp[12] = *(const uint4*)(xpp + 12);
#pragma unroll
            for (int p = 0; p < 16; ++p) {
#pragma unroll
                for (int g = 0; g < 4; ++g)
                    acc[g] = fdot2f(wreg[g][p], xp[p], acc[g]);
            }
        }

        // ---- gather h_t ----
        if (t > 0) {
            const unsigned int want = (unsigned int)t;
            const unsigned long long maddr = (unsigned long long)(
                mir + ((xcd * 2 + (t & 1)) * 1024) + tid * 4);
            uint4 q4;
            if (leader) {
                // tier 1: depth-2 pipelined LLC poll (8 WGs -> no traffic wall)
                unsigned long long b0 = ald(gsrc + 0), b1 = ald(gsrc + 1);
                unsigned long long b2 = ald(gsrc + 2), b3 = ald(gsrc + 3);
                int guard = 0;
                for (;;) {
                    if ((unsigned int)(a0 >> 32) == want &&
                        (unsigned int)(a1 >> 32) == want &&
                        (unsigned int)(a2 >> 32) == want &&
                        (unsigned int)(a3 >> 32) == want) break;
                    if (++guard < (1 << 16)) {
                        a0 = ald(gsrc + 0); a1 = ald(gsrc + 1);
                        a2 = ald(gsrc + 2); a3 = ald(gsrc + 3);
                        if ((unsigned int)(b0 >> 32) == want &&
                            (unsigned int)(b1 >> 32) == want &&
                            (unsigned int)(b2 >> 32) == want &&
                            (unsigned int)(b3 >> 32) == want) {
                            a0 = b0; a1 = b1; a2 = b2; a3 = b3;
                            break;
                        }
                        b0 = ald(gsrc + 0); b1 = ald(gsrc + 1);
                        b2 = ald(gsrc + 2); b3 = ald(gsrc + 3);
                    } else {
                        if (guard >= (1 << 20)) break;   // never hang
                        __builtin_amdgcn_s_sleep(1);
                        a0 = ald(gsrc + 0); a1 = ald(gsrc + 1);
                        a2 = ald(gsrc + 2); a3 = ald(gsrc + 3);
                    }
                }
                // mirror validated u64s into own-XCD L2
                u32x4 mlo, mhi;
                mlo.x = (uint32_t)a0; mlo.y = (uint32_t)(a0 >> 32);
                mlo.z = (uint32_t)a1; mlo.w = (uint32_t)(a1 >> 32);
                mhi.x = (uint32_t)a2; mhi.y = (uint32_t)(a2 >> 32);
                mhi.z = (uint32_t)a3; mhi.w = (uint32_t)(a3 >> 32);
                st32_sc0(maddr, mlo, mhi);
                q4.x = (uint32_t)a0; q4.y = (uint32_t)a1;
                q4.z = (uint32_t)a2; q4.w = (uint32_t)a3;
            } else if (t >= 2 && mirror_ok) {
                // tier 2: poll own-XCD mirror via sc0 (L2-local)
                u32x4 lo, hi;
                int rounds = 0;
                bool ok = false;
                for (;;) {
                    ld32_sc0(maddr, lo, hi);
                    ok = (lo.y == want) & (lo.w == want) &
                         (hi.y == want) & (hi.w == want);
                    if (ok || ++rounds >= MIRROR_ROUNDS) break;
                    __builtin_amdgcn_s_sleep(1);
                }
                if (ok) {
                    q4.x = lo.x; q4.y = lo.z; q4.z = hi.x; q4.w = hi.z;
                } else {
                    // mirror broken for this thread: permanent direct mode
                    mirror_ok = false;
                    int guard = 0;
                    for (;;) {
                        a0 = ald(gsrc + 0); a1 = ald(gsrc + 1);
                        a2 = ald(gsrc + 2); a3 = ald(gsrc + 3);
                        if (((unsigned int)(a0 >> 32) == want) &
                            ((unsigned int)(a1 >> 32) == want) &
                            ((unsigned int)(a2 >> 32) == want) &
                            ((unsigned int)(a3 >> 32) == want)) break;
                        if (++guard >= (1 << 20)) break;   // never hang
                        __builtin_amdgcn_s_sleep(2);
                    }
                    q4.x = (uint32_t)a0; q4.y = (uint32_t)a1;
                    q4.z = (uint32_t)a2; q4.w = (uint32_t)a3;
                }
            } else {
                // direct LLC poll (t==1 for all consumers; sticky fallback)
                int guard = 0;
                for (;;) {
                    if (((unsigned int)(a0 >> 32) == want) &
                        ((unsigned int)(a1 >> 32) == want) &
                        ((unsigned int)(a2 >> 32) == want) &
                        ((unsigned int)(a3 >> 32) == want)) break;
                    if (++guard >= (1 << 20)) break;   // never hang
                    __builtin_amdgcn_s_sleep(2);
                    a0 = ald(gsrc + 0); a1 = ald(gsrc + 1);
                    a2 = ald(gsrc + 2); a3 = ald(gsrc + 3);
                }
                q4.x = (uint32_t)a0; q4.y = (uint32_t)a1;
                q4.z = (uint32_t)a2; q4.w = (uint32_t)a3;
            }
            *(uint4*)&hl[kc * 36 + cg * 4] = q4;
        } else {
            const uint4 z4 = {0u, 0u, 0u, 0u};
            *(uint4*)&hl[kc * 36 + cg * 4] = z4;
        }
        __syncthreads();   // barrier A: hl ready

        // ---- recurrent part ----
        {
            const uint32_t* hp = &hl[kc * 36];
#pragma unroll
            for (int q = 0; q < 8; ++q) {
                const uint4 hv = *(const uint4*)(hp + q * 4);
#pragma unroll
                for (int g = 0; g < 4; ++g) {
                    acc[g] = fdot2f(ureg[g][4 * q + 0], hv.x, acc[g]);
                    acc[g] = fdot2f(ureg[g][4 * q + 1], hv.y, acc[g]);
                    acc[g] = fdot2f(ureg[g][4 * q + 2], hv.z, acc[g]);
                    acc[g] = fdot2f(ureg[g][4 * q + 3], hv.w, acc[g]);
                }
            }
        }

        // ---- butterfly over in-wave kc ----
#pragma unroll
        for (int g = 0; g < 4; ++g) {
            acc[g] += __shfl_xor(acc[g], 8);
            acc[g] += __shfl_xor(acc[g], 16);
            acc[g] += __shfl_xor(acc[g], 32);
        }
        if ((tid & 63) < 8) {
            float4 vv = {acc[0], acc[1], acc[2], acc[3]};
            *(float4*)&zz[(w * 8 + cg) * 4] = vv;
        }
        __syncthreads();   // barrier B: zz ready (also fences hl reuse)

        // ---- final reduce + gates + publish ----
        if (tid < 8) {
            const float4 z0 = *(const float4*)&zz[(0 + cg) * 4];
            const float4 z1 = *(const float4*)&zz[(8 + cg) * 4];
            const float4 z2 = *(const float4*)&zz[(16 + cg) * 4];
            const float4 z3 = *(const float4*)&zz[(24 + cg) * 4];
            const float zi = bias[0] + z0.x + z1.x + z2.x + z3.x;
            const float zf = bias[1] + z0.y + z1.y + z2.y + z3.y;
            const float zg = bias[2] + z0.z + z1.z + z2.z + z3.z;
            const float zo = bias[3] + z0.w + z1.w + z2.w + z3.w;
            const float si = sigmoidf_fast(zi);
            const float sf = sigmoidf_fast(zf);
            const float so = sigmoidf_fast(zo);
            const float cn = sf * cst + si * zg;   // linear candidate act
            cst = cn;
            const float hn = so * cn;              // linear output act
            if (t < S_LEN - 1) {
                const float ha  = __shfl(hn, 2 * cg);
                const float hbv = __shfl(hn, 2 * cg + 1);
                if (cg < 4) {
                    const unsigned long long pv =
                        ((unsigned long long)(unsigned int)(t + 1) << 32) |
                        (unsigned long long)pack2(ha, hbv);
                    unsigned long long* const dst =
                        (((t + 1) & 1) ? hb1 : hb0) + wg * 4 + cg;
                    __hip_atomic_store(dst, pv, __ATOMIC_RELAXED,
                                       __HIP_MEMORY_SCOPE_AGENT);
                }
            } else {
                out[wg * 8 + cg] = hn;
            }
        }
    }
}

extern "C" void kernel_launch(void* const* d_in, const int* in_sizes, int n_in,
                              void* d_out, int out_size, void* d_ws, size_t ws_size,
                              hipStream_t stream) {
    const float* x = (const float*)d_in[0];
    const float* W = (const float*)d_in[1];
    const float* U = (const float*)d_in[2];
    const float* b = (const float*)d_in[3];
    unsigned long long* hbuf = (unsigned long long*)d_ws;

    // Reset hbuf tags (16KB) + mirror (256KB) + election counters (64B)
    // every launch: replays must re-elect and re-synchronize for real.
    (void)hipMemsetAsync(hbuf, 0, (size_t)34816 * 8 + 64, stream);

    hipLaunchKernelGGL(lstm_persist, dim3(NWG), dim3(TPB), 0, stream,
                       x, W, U, b, (float*)d_out, hbuf);
}

// Round 10
// 27892.133 us; speedup vs baseline: 1.0879x; 1.0879x over previous
//
#include <hip/hip_runtime.h>
#include <stdint.h>

// LSTM (linear cell/output act) h_last. S=8192, D_IN=1024, H=2048.
// Persistent: 256 WGs x 256 thr, 1 WG/CU. WG owns 8 h-indices (32 cols).
// Thread (kc=tid>>3, cg=tid&7): 4 gate-cols of h-index cg, k-chunk kc.
//   U slice in regs ureg[4][32], W slice in regs wreg[4][16] (f16x2).
// EXCHANGE (r10): counter-hint detect + one verified bulk gather.
//   publish: 4x u64 {tag32|f16x2} relaxed agent stores (as r5), then tid0
//            relaxed atomicAdd(+1) to cnt[wg>>5] (8 counters on 8 lines,
//            monotonic: cnt[g]==32*(steps done by group g)).
//   detect:  wave0 lanes0-7 poll the 8 counters (__all(cnt>=32t)) — only
//            2K requests/round DEVICE-WIDE (vs r5's 262K) — lane0 raises a
//            monotonic LDS flag; waves1-3 spin on LDS.
//   gather:  on flag, each thread does ONE 32B dwordx4x2 sc0sc1 read of its
//            producer's slots, verifies all 4 tags (counter is only a hint;
//            tags are the guarantee), rare paced micro-retry.
// POST-MORTEM LEDGER:
//  - r2: partial unroll -> ureg/wreg in scratch (VGPR=80, 207GB fetch, 2.7x).
//  - r3: guarded per-slot polls serialize (8 x LLC latency/round).
//  - r4: 64B tight polls -> contention collapse (38ms).
//  - r5: 32B + sleep(2) = 26.2ms best flat design.
//  - r6: depth-2 no-sleep -> 32.3ms. Poll REQUEST RATE is controlling:
//    ~262K req/round saturates LLC request service -> latency inflates ~2Kcy.
//  - r7: 8B tag + 32B confirm = 27.7ms. Flat poll floor ~7.5Kcy/step.
//  - r8/r9: sc0 XCD-L2 mirror never engaged (sticky fallback ≈ r5+overhead);
//    XCC_ID/sc0-visibility assumptions unverifiable here. Abandoned.

#define S_LEN   8192
#define D_INP   1024
#define HDIM    2048
#define FH      8192
#define NWG     256
#define TPB     256
#define XB      8

typedef _Float16 half2_t __attribute__((ext_vector_type(2)));
typedef uint32_t u32x4   __attribute__((ext_vector_type(4)));

#if defined(__has_builtin)
#if __has_builtin(__builtin_amdgcn_fdot2)
#define HAVE_FDOT2 1
#endif
#endif

__device__ __forceinline__ float fdot2f(uint32_t a, uint32_t b, float c) {
#ifdef HAVE_FDOT2
    return __builtin_amdgcn_fdot2(__builtin_bit_cast(half2_t, a),
                                  __builtin_bit_cast(half2_t, b), c, false);
#else
    half2_t ha = __builtin_bit_cast(half2_t, a);
    half2_t hb = __builtin_bit_cast(half2_t, b);
    c = fmaf((float)ha.x, (float)hb.x, c);
    c = fmaf((float)ha.y, (float)hb.y, c);
    return c;
#endif
}

__device__ __forceinline__ uint32_t pack2(float a, float b) {
    half2_t h;
    h.x = (_Float16)a;
    h.y = (_Float16)b;
    return __builtin_bit_cast(uint32_t, h);
}

__device__ __forceinline__ float sigmoidf_fast(float z) {
    return 1.0f / (1.0f + __expf(-z));
}

// 32B LLC-coherent load (sc0 sc1: bypass L1 and non-coherent L2).
__device__ __forceinline__ void ld32_llc(unsigned long long addr,
                                         u32x4& lo, u32x4& hi) {
    asm volatile("global_load_dwordx4 %0, %2, off sc0 sc1\n\t"
                 "global_load_dwordx4 %1, %2, off offset:16 sc0 sc1\n\t"
                 "s_waitcnt vmcnt(0)"
                 : "=&v"(lo), "=&v"(hi)
                 : "v"(addr)
                 : "memory");
}

extern "C" __global__ void __launch_bounds__(TPB, 1)
lstm_persist(const float* __restrict__ x, const float* __restrict__ W,
             const float* __restrict__ U, const float* __restrict__ b,
             float* __restrict__ out, unsigned long long* __restrict__ hbuf)
{
    __shared__ __align__(16) uint32_t xl[XB * 640];
    __shared__ __align__(16) uint32_t hl[32 * 36];
    __shared__ __align__(16) float    zz[4 * 8 * 4];
    __shared__ int sflag;   // monotonic "step t data detected" flag

    const int tid = threadIdx.x;
    const int wg  = blockIdx.x;
    const int cg  = tid & 7;
    const int kc  = tid >> 3;
    const int w   = tid >> 6;

    if (tid == 0) sflag = 0;   // first read is at t=1, after >=3 barriers

    // ws layout (u64 units): [0..2047] data slots | [2048..2111] counters
    unsigned int* const cnt = (unsigned int*)(hbuf + 2048);  // cnt[g*16]

    // ---- one-time: weights -> registers (FULL unroll, static indices) ----
    uint32_t ureg[4][32];
    uint32_t wreg[4][16];
#pragma unroll
    for (int g = 0; g < 4; ++g) {
        const int col = g * HDIM + wg * 8 + cg;
#pragma unroll
        for (int p = 0; p < 32; ++p) {
            const int k0 = kc * 64 + 2 * p;
            ureg[g][p] = pack2(U[(size_t)k0 * FH + col],
                               U[(size_t)(k0 + 1) * FH + col]);
        }
#pragma unroll
        for (int p = 0; p < 16; ++p) {
            const int k0 = kc * 32 + 2 * p;
            wreg[g][p] = pack2(W[(size_t)k0 * FH + col],
                               W[(size_t)(k0 + 1) * FH + col]);
        }
    }
    float bias[4] = {0.f, 0.f, 0.f, 0.f};
    if (tid < 8) {
#pragma unroll
        for (int g = 0; g < 4; ++g) bias[g] = b[g * HDIM + wg * 8 + cg];
    }
    float cst = 0.0f;   // cell state for h-index cg (valid on tid<8)

    // ---- x prefetch regs: row r = tid>>5, chunk kcw = tid&31 ----
    const int xr  = tid >> 5;
    const int kcw = tid & 31;
    float4 pf[8];
    {
        const float4* src = (const float4*)(x + (size_t)xr * D_INP + kcw * 32);
#pragma unroll
        for (int q = 0; q < 8; ++q) pf[q] = src[q];
    }

    unsigned long long* const hb0 = hbuf;
    unsigned long long* const hb1 = hbuf + 1024;

    for (int t = 0; t < S_LEN; ++t) {
        const int s = t & (XB - 1);
        if (s == 0) {
            // commit prefetched x rows [t, t+8) to LDS as f16x2
            uint32_t* dst = &xl[xr * 640 + kcw * 20];
#pragma unroll
            for (int q = 0; q < 4; ++q) {
                uint4 v;
                v.x = pack2(pf[2 * q].x, pf[2 * q].y);
                v.y = pack2(pf[2 * q].z, pf[2 * q].w);
                v.z = pack2(pf[2 * q + 1].x, pf[2 * q + 1].y);
                v.w = pack2(pf[2 * q + 1].z, pf[2 * q + 1].w);
                *(uint4*)(dst + q * 4) = v;
            }
            __syncthreads();
            if (t + XB < S_LEN) {   // issue next block's loads (8 steps ahead)
                const float4* src = (const float4*)(
                    x + (size_t)(t + XB + xr) * D_INP + kcw * 32);
#pragma unroll
                for (int q = 0; q < 8; ++q) pf[q] = src[q];
            }
        }

        // ---- x-part: acc[g] = sum_k x_t[k] * W[k, col(g)] ----
        float acc[4] = {0.f, 0.f, 0.f, 0.f};
        {
            uint32_t xp[16];
            const uint32_t* xpp = &xl[s * 640 + kc * 20];
            *(uint4*)&xp[0]  = *(const uint4*)(xpp + 0);
            *(uint4*)&xp[4]  = *(const uint4*)(xpp + 4);
            *(uint4*)&xp[8]  = *(const uint4*)(xpp + 8);
            *(uint4*)&xp[12] = *(const uint4*)(xpp + 12);
#pragma unroll
            for (int p = 0; p < 16; ++p) {
#pragma unroll
                for (int g = 0; g < 4; ++g)
                    acc[g] = fdot2f(wreg[g][p], xp[p], acc[g]);
            }
        }

        // ---- gather h_t: counter-hint detect + one verified 32B read ----
        if (t > 0) {
            const unsigned int want = (unsigned int)t;
            if (tid < 64) {
                // wave 0: lanes 0-7 poll the 8 group counters
                const unsigned int need = 32u * want;
                int guard = 0;
                for (;;) {
                    unsigned int c = 0xFFFFFFFFu;
                    if (tid < 8)
                        c = __hip_atomic_load(&cnt[tid * 16], __ATOMIC_RELAXED,
                                              __HIP_MEMORY_SCOPE_AGENT);
                    if (__all((tid < 8) ? (c >= need) : 1)) break;
                    if (++guard >= (1 << 20)) break;   // never hang
                    __builtin_amdgcn_s_sleep(1);
                }
                if (tid == 0)
                    __hip_atomic_store(&sflag, t, __ATOMIC_RELAXED,
                                       __HIP_MEMORY_SCOPE_WORKGROUP);
            } else {
                // waves 1-3: cheap local spin on LDS flag
                int guard = 0;
                while (__hip_atomic_load(&sflag, __ATOMIC_RELAXED,
                                         __HIP_MEMORY_SCOPE_WORKGROUP) < t) {
                    if (++guard >= (1 << 20)) break;   // never hang
                    __builtin_amdgcn_s_sleep(1);
                }
            }
            // one 32B bulk read of own producer's slots; tags verify
            const unsigned long long gaddr =
                (unsigned long long)(((t & 1) ? hb1 : hb0) + tid * 4);
            u32x4 lo, hi;
            int guard = 0;
            for (;;) {
                ld32_llc(gaddr, lo, hi);
                const bool ok = (lo.y == want) & (lo.w == want) &
                                (hi.y == want) & (hi.w == want);
                if (ok || ++guard >= (1 << 20)) break;   // never hang
                __builtin_amdgcn_s_sleep(1);             // rare: skew tail
            }
            uint4 q4;
            q4.x = lo.x; q4.y = lo.z; q4.z = hi.x; q4.w = hi.z;
            *(uint4*)&hl[kc * 36 + cg * 4] = q4;   // (tid>>3, tid&7)
        } else {
            const uint4 z4 = {0u, 0u, 0u, 0u};
            *(uint4*)&hl[kc * 36 + cg * 4] = z4;
        }
        __syncthreads();   // barrier A: hl ready

        // ---- recurrent part: acc[g] += sum_k h_t[k] * U[k, col(g)] ----
        {
            const uint32_t* hp = &hl[kc * 36];
#pragma unroll
            for (int q = 0; q < 8; ++q) {
                const uint4 hv = *(const uint4*)(hp + q * 4);
#pragma unroll
                for (int g = 0; g < 4; ++g) {
                    acc[g] = fdot2f(ureg[g][4 * q + 0], hv.x, acc[g]);
                    acc[g] = fdot2f(ureg[g][4 * q + 1], hv.y, acc[g]);
                    acc[g] = fdot2f(ureg[g][4 * q + 2], hv.z, acc[g]);
                    acc[g] = fdot2f(ureg[g][4 * q + 3], hv.w, acc[g]);
                }
            }
        }

        // ---- butterfly over in-wave kc (tid bits 3..5) ----
#pragma unroll
        for (int g = 0; g < 4; ++g) {
            acc[g] += __shfl_xor(acc[g], 8);
            acc[g] += __shfl_xor(acc[g], 16);
            acc[g] += __shfl_xor(acc[g], 32);
        }
        if ((tid & 63) < 8) {
            float4 vv = {acc[0], acc[1], acc[2], acc[3]};
            *(float4*)&zz[(w * 8 + cg) * 4] = vv;
        }
        __syncthreads();   // barrier B: zz ready (also fences hl reuse)

        // ---- final reduce + gates + publish (threads 0..7) ----
        if (tid < 8) {
            const float4 z0 = *(const float4*)&zz[(0 + cg) * 4];
            const float4 z1 = *(const float4*)&zz[(8 + cg) * 4];
            const float4 z2 = *(const float4*)&zz[(16 + cg) * 4];
            const float4 z3 = *(const float4*)&zz[(24 + cg) * 4];
            const float zi = bias[0] + z0.x + z1.x + z2.x + z3.x;
            const float zf = bias[1] + z0.y + z1.y + z2.y + z3.y;
            const float zg = bias[2] + z0.z + z1.z + z2.z + z3.z;
            const float zo = bias[3] + z0.w + z1.w + z2.w + z3.w;
            const float si = sigmoidf_fast(zi);
            const float sf = sigmoidf_fast(zf);
            const float so = sigmoidf_fast(zo);
            const float cn = sf * cst + si * zg;   // linear candidate act
            cst = cn;
            const float hn = so * cn;              // linear output act
            if (t < S_LEN - 1) {
                // pack pairs: lane j<4 publishes {tag, h[2j], h[2j+1]}
                const float ha  = __shfl(hn, 2 * cg);
                const float hbv = __shfl(hn, 2 * cg + 1);
                if (cg < 4) {
                    const unsigned long long pv =
                        ((unsigned long long)(unsigned int)(t + 1) << 32) |
                        (unsigned long long)pack2(ha, hbv);
                    unsigned long long* const dst =
                        (((t + 1) & 1) ? hb1 : hb0) + wg * 4 + cg;
                    __hip_atomic_store(dst, pv, __ATOMIC_RELAXED,
                                       __HIP_MEMORY_SCOPE_AGENT);
                }
                // hint counter: fire-and-forget after the 4 slot stores
                if (tid == 0)
                    __hip_atomic_fetch_add(&cnt[(wg >> 5) * 16], 1u,
                                           __ATOMIC_RELAXED,
                                           __HIP_MEMORY_SCOPE_AGENT);
            } else {
                out[wg * 8 + cg] = hn;
            }
        }
    }
}

extern "C" void kernel_launch(void* const* d_in, const int* in_sizes, int n_in,
                              void* d_out, int out_size, void* d_ws, size_t ws_size,
                              hipStream_t stream) {
    const float* x = (const float*)d_in[0];
    const float* W = (const float*)d_in[1];
    const float* U = (const float*)d_in[2];
    const float* b = (const float*)d_in[3];
    unsigned long long* hbuf = (unsigned long long*)d_ws;

    // Reset data tags (16KB) + counters (512B) every launch: replays must
    // re-synchronize for real (counters are monotonic from 0 each launch).
    (void)hipMemsetAsync(hbuf, 0, (size_t)17408, stream);

    hipLaunchKernelGGL(lstm_persist, dim3(NWG), dim3(TPB), 0, stream,
                       x, W, U, b, (float*)d_out, hbuf);
}

// Round 11
// 18132.181 us; speedup vs baseline: 1.6734x; 1.5383x over previous
//
#include <hip/hip_runtime.h>
#include <stdint.h>

// LSTM (linear cell/output act) h_last. S=8192, D_IN=1024, H=2048.
// Persistent: 256 WGs x 256 thr, 1 WG/CU. WG owns 8 h-indices (32 cols).
// Thread (kc=tid>>3, cg=tid&7): 4 gate-cols of h-index cg, k-chunk kc.
//   U slice in regs ureg[4][32], W slice in regs wreg[4][16] (f16x2).
// Exchange: producer WG publishes 8 h as FOUR u64 {tag32|f16x2} (32 B, r5).
// GATHER (r11): ADAPTIVE-PACE SINGLE-SHOT. The step cadence is barrier-locked
// and stable, so transit is predictable: sleep pace x s_sleep(1), issue ONE
// 32B batch, check once after the x-dot. Wave-uniform controller
// (miss: pace+=8, first-check hit: pace-=1) hovers at the hit boundary ->
// ~300cy overshoot instead of r5's ~1-1.5Kcy blind-poll waste. Fallback on
// miss = r5's exact paced poll.
// POST-MORTEM LEDGER:
//  - r2: partial unroll -> ureg/wreg in scratch (VGPR=80, 207GB fetch, 2.7x).
//  - r3: guarded per-slot polls serialize (8 x LLC latency/round).
//  - r4: 64B tight polls -> contention collapse (38ms).
//  - r5: 32B + sleep(2) = 26.2ms best flat design.
//  - r6: depth-2 no-sleep -> 32.3ms (traffic storm).
//  - r7: 8B tag + 32B confirm = 27.7ms (extra serial RT).
//  - r8/r9: sc0 XCD-L2 mirror never engaged; abandoned.
//  - r10: counter-hint detect = 27.9ms NULL with 130x fewer poll requests ->
//    poll TRAFFIC exonerated; 2nd serial RT (detect then read) hurts.
//    Remaining attackable term: poll-phase waste -> this round.

#define S_LEN   8192
#define D_INP   1024
#define HDIM    2048
#define FH      8192
#define NWG     256
#define TPB     256
#define XB      8
#define PACE_MAX 120

typedef _Float16 half2_t __attribute__((ext_vector_type(2)));

#if defined(__has_builtin)
#if __has_builtin(__builtin_amdgcn_fdot2)
#define HAVE_FDOT2 1
#endif
#endif

__device__ __forceinline__ float fdot2f(uint32_t a, uint32_t b, float c) {
#ifdef HAVE_FDOT2
    return __builtin_amdgcn_fdot2(__builtin_bit_cast(half2_t, a),
                                  __builtin_bit_cast(half2_t, b), c, false);
#else
    half2_t ha = __builtin_bit_cast(half2_t, a);
    half2_t hb = __builtin_bit_cast(half2_t, b);
    c = fmaf((float)ha.x, (float)hb.x, c);
    c = fmaf((float)ha.y, (float)hb.y, c);
    return c;
#endif
}

__device__ __forceinline__ uint32_t pack2(float a, float b) {
    half2_t h;
    h.x = (_Float16)a;
    h.y = (_Float16)b;
    return __builtin_bit_cast(uint32_t, h);
}

__device__ __forceinline__ float sigmoidf_fast(float z) {
    return 1.0f / (1.0f + __expf(-z));
}

__device__ __forceinline__ unsigned long long ald(const unsigned long long* p) {
    return __hip_atomic_load(p, __ATOMIC_RELAXED, __HIP_MEMORY_SCOPE_AGENT);
}

extern "C" __global__ void __launch_bounds__(TPB, 1)
lstm_persist(const float* __restrict__ x, const float* __restrict__ W,
             const float* __restrict__ U, const float* __restrict__ b,
             float* __restrict__ out, unsigned long long* __restrict__ hbuf)
{
    // xl: 8 rows x 32 chunks x 20 words (16 used) = 20 KB
    // hl: 32 chunks x 36 words (32 used)          = 4.5 KB
    // zz: [wave][cg][gate] floats                  = 0.5 KB
    __shared__ __align__(16) uint32_t xl[XB * 640];
    __shared__ __align__(16) uint32_t hl[32 * 36];
    __shared__ __align__(16) float    zz[4 * 8 * 4];

    const int tid = threadIdx.x;
    const int wg  = blockIdx.x;
    const int cg  = tid & 7;     // h-index within WG octet
    const int kc  = tid >> 3;    // k-chunk 0..31
    const int w   = tid >> 6;    // wave 0..3

    // ---- one-time: weights -> registers (FULL unroll, static indices) ----
    uint32_t ureg[4][32];
    uint32_t wreg[4][16];
#pragma unroll
    for (int g = 0; g < 4; ++g) {
        const int col = g * HDIM + wg * 8 + cg;
#pragma unroll
        for (int p = 0; p < 32; ++p) {
            const int k0 = kc * 64 + 2 * p;
            ureg[g][p] = pack2(U[(size_t)k0 * FH + col],
                               U[(size_t)(k0 + 1) * FH + col]);
        }
#pragma unroll
        for (int p = 0; p < 16; ++p) {
            const int k0 = kc * 32 + 2 * p;
            wreg[g][p] = pack2(W[(size_t)k0 * FH + col],
                               W[(size_t)(k0 + 1) * FH + col]);
        }
    }
    float bias[4] = {0.f, 0.f, 0.f, 0.f};
    if (tid < 8) {
#pragma unroll
        for (int g = 0; g < 4; ++g) bias[g] = b[g * HDIM + wg * 8 + cg];
    }
    float cst = 0.0f;   // cell state for h-index cg (valid on tid<8)

    // ---- x prefetch regs: row r = tid>>5, chunk kcw = tid&31 ----
    const int xr  = tid >> 5;
    const int kcw = tid & 31;
    float4 pf[8];
    {
        const float4* src = (const float4*)(x + (size_t)xr * D_INP + kcw * 32);
#pragma unroll
        for (int q = 0; q < 8; ++q) pf[q] = src[q];
    }

    // hbuf: 2 parity buffers x 256 producers x 4 u64 {tag32|f16x2}
    unsigned long long* const hb0 = hbuf;
    unsigned long long* const hb1 = hbuf + 1024;

    int pace = 0;   // adaptive pre-sleep units (wave-uniform updates)

    for (int t = 0; t < S_LEN; ++t) {
        const int s = t & (XB - 1);
        if (s == 0) {
            // commit prefetched x rows [t, t+8) to LDS as f16x2
            uint32_t* dst = &xl[xr * 640 + kcw * 20];
#pragma unroll
            for (int q = 0; q < 4; ++q) {
                uint4 v;
                v.x = pack2(pf[2 * q].x, pf[2 * q].y);
                v.y = pack2(pf[2 * q].z, pf[2 * q].w);
                v.z = pack2(pf[2 * q + 1].x, pf[2 * q + 1].y);
                v.w = pack2(pf[2 * q + 1].z, pf[2 * q + 1].w);
                *(uint4*)(dst + q * 4) = v;
            }
            __syncthreads();
            if (t + XB < S_LEN) {   // issue next block's loads (8 steps ahead)
                const float4* src = (const float4*)(
                    x + (size_t)(t + XB + xr) * D_INP + kcw * 32);
#pragma unroll
                for (int q = 0; q < 8; ++q) pf[q] = src[q];
            }
        }

        // ---- calibrated pre-sleep, then issue the single gather batch ----
        unsigned long long* const gsrc = ((t & 1) ? hb1 : hb0) + tid * 4;
        unsigned long long a0, a1, a2, a3;
        if (t > 0) {
            for (int i = 0; i < pace; ++i) __builtin_amdgcn_s_sleep(1);
            a0 = ald(gsrc + 0); a1 = ald(gsrc + 1);
            a2 = ald(gsrc + 2); a3 = ald(gsrc + 3);
        }

        // ---- x-part: acc[g] = sum_k x_t[k] * W[k, col(g)] (loads fly) ----
        float acc[4] = {0.f, 0.f, 0.f, 0.f};
        {
            uint32_t xp[16];
            const uint32_t* xpp = &xl[s * 640 + kc * 20];
            *(uint4*)&xp[0]  = *(const uint4*)(xpp + 0);
            *(uint4*)&xp[4]  = *(const uint4*)(xpp + 4);
            *(uint4*)&xp[8]  = *(const uint4*)(xpp + 8);
            *(uint4*)&xp[12] = *(const uint4*)(xpp + 12);
#pragma unroll
            for (int p = 0; p < 16; ++p) {
#pragma unroll
                for (int g = 0; g < 4; ++g)
                    acc[g] = fdot2f(wreg[g][p], xp[p], acc[g]);
            }
        }

        // ---- gather h_t: single-shot check + controller + fallback poll ----
        if (t > 0) {
            const unsigned int want = (unsigned int)t;
            const bool hit = ((unsigned int)(a0 >> 32) == want) &
                             ((unsigned int)(a1 >> 32) == want) &
                             ((unsigned int)(a2 >> 32) == want) &
                             ((unsigned int)(a3 >> 32) == want);
            if (__all(hit)) {
                if (pace > 0) pace -= 1;      // shrink slowly toward boundary
            } else {
                pace = (pace + 8 > PACE_MAX) ? PACE_MAX : pace + 8;
                int guard = 0;
                for (;;) {                     // r5 fallback poll
                    a0 = ald(gsrc + 0); a1 = ald(gsrc + 1);
                    a2 = ald(gsrc + 2); a3 = ald(gsrc + 3);
                    const bool ok = ((unsigned int)(a0 >> 32) == want) &
                                    ((unsigned int)(a1 >> 32) == want) &
                                    ((unsigned int)(a2 >> 32) == want) &
                                    ((unsigned int)(a3 >> 32) == want);
                    if (ok || ++guard >= (1 << 20)) break;   // never hang
                    __builtin_amdgcn_s_sleep(1);
                }
            }
            uint4 q4;
            q4.x = (unsigned int)a0;   // low u32 IS the f16x2 hl word
            q4.y = (unsigned int)a1;
            q4.z = (unsigned int)a2;
            q4.w = (unsigned int)a3;
            *(uint4*)&hl[kc * 36 + cg * 4] = q4;   // (tid>>3, tid&7)
        } else {
            const uint4 z4 = {0u, 0u, 0u, 0u};
            *(uint4*)&hl[kc * 36 + cg * 4] = z4;
        }
        __syncthreads();   // barrier A: hl ready

        // ---- recurrent part: acc[g] += sum_k h_t[k] * U[k, col(g)] ----
        {
            const uint32_t* hp = &hl[kc * 36];
#pragma unroll
            for (int q = 0; q < 8; ++q) {
                const uint4 hv = *(const uint4*)(hp + q * 4);
#pragma unroll
                for (int g = 0; g < 4; ++g) {
                    acc[g] = fdot2f(ureg[g][4 * q + 0], hv.x, acc[g]);
                    acc[g] = fdot2f(ureg[g][4 * q + 1], hv.y, acc[g]);
                    acc[g] = fdot2f(ureg[g][4 * q + 2], hv.z, acc[g]);
                    acc[g] = fdot2f(ureg[g][4 * q + 3], hv.w, acc[g]);
                }
            }
        }

        // ---- butterfly over in-wave kc (tid bits 3..5) ----
#pragma unroll
        for (int g = 0; g < 4; ++g) {
            acc[g] += __shfl_xor(acc[g], 8);
            acc[g] += __shfl_xor(acc[g], 16);
            acc[g] += __shfl_xor(acc[g], 32);
        }
        if ((tid & 63) < 8) {
            float4 vv = {acc[0], acc[1], acc[2], acc[3]};
            *(float4*)&zz[(w * 8 + cg) * 4] = vv;
        }
        __syncthreads();   // barrier B: zz ready (also fences hl reuse)

        // ---- final reduce + gates + publish (threads 0..7) ----
        if (tid < 8) {
            const float4 z0 = *(const float4*)&zz[(0 + cg) * 4];
            const float4 z1 = *(const float4*)&zz[(8 + cg) * 4];
            const float4 z2 = *(const float4*)&zz[(16 + cg) * 4];
            const float4 z3 = *(const float4*)&zz[(24 + cg) * 4];
            const float zi = bias[0] + z0.x + z1.x + z2.x + z3.x;
            const float zf = bias[1] + z0.y + z1.y + z2.y + z3.y;
            const float zg = bias[2] + z0.z + z1.z + z2.z + z3.z;
            const float zo = bias[3] + z0.w + z1.w + z2.w + z3.w;
            const float si = sigmoidf_fast(zi);
            const float sf = sigmoidf_fast(zf);
            const float so = sigmoidf_fast(zo);
            const float cn = sf * cst + si * zg;   // linear candidate act
            cst = cn;
            const float hn = so * cn;              // linear output act
            if (t < S_LEN - 1) {
                // pack pairs: lane j<4 publishes {tag, h[2j], h[2j+1]}
                const float ha  = __shfl(hn, 2 * cg);
                const float hbv = __shfl(hn, 2 * cg + 1);
                if (cg < 4) {
                    const unsigned long long pv =
                        ((unsigned long long)(unsigned int)(t + 1) << 32) |
                        (unsigned long long)pack2(ha, hbv);
                    unsigned long long* const dst =
                        (((t + 1) & 1) ? hb1 : hb0) + wg * 4 + cg;
                    __hip_atomic_store(dst, pv, __ATOMIC_RELAXED,
                                       __HIP_MEMORY_SCOPE_AGENT);
                }
            } else {
                out[wg * 8 + cg] = hn;
            }
        }
    }
}

extern "C" void kernel_launch(void* const* d_in, const int* in_sizes, int n_in,
                              void* d_out, int out_size, void* d_ws, size_t ws_size,
                              hipStream_t stream) {
    const float* x = (const float*)d_in[0];
    const float* W = (const float*)d_in[1];
    const float* U = (const float*)d_in[2];
    const float* b = (const float*)d_in[3];
    unsigned long long* hbuf = (unsigned long long*)d_ws;

    // Reset exchange tags every launch (replays must re-synchronize for real).
    (void)hipMemsetAsync(hbuf, 0, (size_t)2 * 1024 * sizeof(unsigned long long),
                         stream);

    hipLaunchKernelGGL(lstm_persist, dim3(NWG), dim3(TPB), 0, stream,
                       x, W, U, b, (float*)d_out, hbuf);
}